// Round 4
// baseline (153.985 us; speedup 1.0000x reference)
//
#include <hip/hip_runtime.h>

#define BB 4
#define SS 4096
#define DD 512
#define BLK 64
#define NBLK (SS / BLK)            // 64 blocks per sequence
#define COMPUTE_WGS (BB * NBLK)    // 256
#define NFILL 4096                 // fill workgroups (pure-write kernel)

#define ATTN_F4 ((unsigned)BB * SS * SS / 4)          // 16,777,216 float4s
#define MASK_F4 ((unsigned)SS * SS / 4)               //  4,194,304 float4s
#define TOT_F4  (ATTN_F4 + MASK_F4)                   // 20,971,520 float4s
// TOT_F4 / (NFILL*256) == 20 exactly -> no bounds check needed

// native vector type for nontemporal builtins
typedef float nf4 __attribute__((ext_vector_type(4)));

static __device__ __forceinline__ void nt_store4(float* p, float x, float y, float z, float w) {
    nf4 v = {x, y, z, w};
    __builtin_nontemporal_store(v, (nf4*)p);
}
static __device__ __forceinline__ void nt_splat4(float* p, float x) {
    nf4 v = {x, x, x, x};
    __builtin_nontemporal_store(v, (nf4*)p);
}

// ---------------- K2: pure streaming fill (attn zeros + mask) ----------------
__global__ __launch_bounds__(256)
void fill_kernel(float* __restrict__ out)
{
    float* const attn = out + (size_t)BB * SS * DD;
    const unsigned stride = (unsigned)NFILL * 256u;
    unsigned f = blockIdx.x * 256u + threadIdx.x;
    #pragma unroll 4
    for (int it = 0; it < 20; ++it, f += stride) {
        if (f < ATTN_F4) {
            const unsigned row = f >> 10;                    // 0..16383
            const unsigned c4b = (f & 1023u) >> 4;           // 16-f4 segment in row
            const unsigned qb  = (row & (SS - 1u)) >> 6;     // row's block
            if (c4b != qb) nt_splat4(&attn[(size_t)f * 4], 0.0f);
        } else {
            const unsigned g   = f - ATTN_F4;
            const unsigned row = g >> 10;                    // 0..4095
            const unsigned c4b = (g & 1023u) >> 4;
            nt_splat4(&attn[(size_t)f * 4], (c4b == (row >> 6)) ? 1.0f : 0.0f);
        }
    }
}

// ---------------- K1: block-local attention compute ----------------
__global__ __launch_bounds__(256)
void compute_kernel(const float* __restrict__ q,
                    const float* __restrict__ k,
                    const float* __restrict__ v,
                    float* __restrict__ out)
{
    const float SCALE = 0.044194173824159216f;  // 1/sqrt(512)
    const int wg = blockIdx.x;
    const int t  = threadIdx.x;

    float* const attn = out + (size_t)BB * SS * DD;

    const int b   = wg >> 6;
    const int blk = wg & 63;
    const int q0  = blk * BLK;

    const float* Q = q + ((size_t)(b * SS + q0)) * DD;
    const float* K = k + ((size_t)(b * SS + q0)) * DD;
    const float* V = v + ((size_t)(b * SS + q0)) * DD;
    float* O = out + ((size_t)(b * SS + q0)) * DD;
    float* A = attn + (size_t)b * SS * SS + (size_t)q0 * SS + q0;

    __shared__ float qs[64][68];   // Q chunk; reused as P after scores
    __shared__ float ks[64][68];   // K chunk; reused as V chunk

    const int rg = t >> 4;         // row group 0..15 -> rows rg*4 + m
    const int cg = t & 15;         // col group 0..15

    // per-thread staging coordinates (4 float4s, covers 64x64 chunk)
    int srow[4], sc4[4];
    #pragma unroll
    for (int i = 0; i < 4; ++i) {
        const int f4 = t + i * 256;
        srow[i] = f4 >> 4;
        sc4[i]  = (f4 & 15) * 4;
    }

    float acc[4][4];
    #pragma unroll
    for (int m = 0; m < 4; ++m)
        #pragma unroll
        for (int n = 0; n < 4; ++n) acc[m][n] = 0.0f;

    // ---- phase 1: scores S = Q K^T, register double-buffered staging ----
    float4 pq[4], pk[4];
    #pragma unroll
    for (int i = 0; i < 4; ++i) {
        pq[i] = *(const float4*)&Q[(size_t)srow[i] * DD + sc4[i]];
        pk[i] = *(const float4*)&K[(size_t)srow[i] * DD + sc4[i]];
    }
    #pragma unroll
    for (int ch = 0; ch < 8; ++ch) {
        #pragma unroll
        for (int i = 0; i < 4; ++i) {
            *(float4*)&qs[srow[i]][sc4[i]] = pq[i];
            *(float4*)&ks[srow[i]][sc4[i]] = pk[i];
        }
        if (ch < 7) {
            const int dcn = (ch + 1) * 64;
            #pragma unroll
            for (int i = 0; i < 4; ++i) {
                pq[i] = *(const float4*)&Q[(size_t)srow[i] * DD + dcn + sc4[i]];
                pk[i] = *(const float4*)&K[(size_t)srow[i] * DD + dcn + sc4[i]];
            }
        }
        __syncthreads();
        #pragma unroll
        for (int c4 = 0; c4 < 64; c4 += 4) {
            float4 qv[4], kv[4];
            #pragma unroll
            for (int m = 0; m < 4; ++m) qv[m] = *(const float4*)&qs[rg * 4 + m][c4];
            #pragma unroll
            for (int n = 0; n < 4; ++n) kv[n] = *(const float4*)&ks[cg + 16 * n][c4];
            #pragma unroll
            for (int m = 0; m < 4; ++m)
                #pragma unroll
                for (int n = 0; n < 4; ++n)
                    acc[m][n] += qv[m].x * kv[n].x + qv[m].y * kv[n].y
                               + qv[m].z * kv[n].z + qv[m].w * kv[n].w;
        }
        __syncthreads();
    }

    // issue V chunk-0 loads; latency hides under softmax
    float4 pv[4];
    #pragma unroll
    for (int i = 0; i < 4; ++i)
        pv[i] = *(const float4*)&V[(size_t)srow[i] * DD + sc4[i]];

    // ---- phase 2: softmax over each row's 64 in-block scores ----
    float p[4][4];
    #pragma unroll
    for (int m = 0; m < 4; ++m) {
        float mx = -1e30f;
        #pragma unroll
        for (int n = 0; n < 4; ++n) {
            acc[m][n] *= SCALE;
            mx = fmaxf(mx, acc[m][n]);
        }
        #pragma unroll
        for (int s = 1; s < 16; s <<= 1) mx = fmaxf(mx, __shfl_xor(mx, s, 64));
        float sum = 0.0f;
        #pragma unroll
        for (int n = 0; n < 4; ++n) {
            p[m][n] = __expf(acc[m][n] - mx);
            sum += p[m][n];
        }
        #pragma unroll
        for (int s = 1; s < 16; s <<= 1) sum += __shfl_xor(sum, s, 64);
        const float inv = 1.0f / sum;
        #pragma unroll
        for (int n = 0; n < 4; ++n) p[m][n] *= inv;
    }

    // stash P in LDS (reuse qs), then write attn band rows as float4
    #pragma unroll
    for (int m = 0; m < 4; ++m) {
        const int row = rg * 4 + m;
        #pragma unroll
        for (int n = 0; n < 4; ++n) qs[row][cg + 16 * n] = p[m][n];
    }
    __syncthreads();
    #pragma unroll
    for (int i = 0; i < 4; ++i) {
        const int j   = t + i * 256;
        const int row = j >> 4;
        const int c4  = (j & 15) * 4;
        nt_store4(&A[(size_t)row * SS + c4],
                  qs[row][c4], qs[row][c4 + 1], qs[row][c4 + 2], qs[row][c4 + 3]);
    }

    // ---- phase 3: O = P V, register double-buffered V staging ----
    #pragma unroll
    for (int ch = 0; ch < 8; ++ch) {
        const int dc = ch * 64;
        #pragma unroll
        for (int i = 0; i < 4; ++i)
            *(float4*)&ks[srow[i]][sc4[i]] = pv[i];
        if (ch < 7) {
            const int dcn = dc + 64;
            #pragma unroll
            for (int i = 0; i < 4; ++i)
                pv[i] = *(const float4*)&V[(size_t)srow[i] * DD + dcn + sc4[i]];
        }
        __syncthreads();
        float o[4][4];
        #pragma unroll
        for (int m = 0; m < 4; ++m)
            #pragma unroll
            for (int n = 0; n < 4; ++n) o[m][n] = 0.0f;
        #pragma unroll
        for (int k4 = 0; k4 < 64; k4 += 4) {
            float4 pw[4];
            #pragma unroll
            for (int m = 0; m < 4; ++m) pw[m] = *(const float4*)&qs[rg * 4 + m][k4];
            #pragma unroll
            for (int kk = 0; kk < 4; ++kk) {
                const float4 vv = *(const float4*)&ks[k4 + kk][cg * 4];
                #pragma unroll
                for (int m = 0; m < 4; ++m) {
                    const float pm = ((const float*)&pw[m])[kk];
                    o[m][0] += pm * vv.x;
                    o[m][1] += pm * vv.y;
                    o[m][2] += pm * vv.z;
                    o[m][3] += pm * vv.w;
                }
            }
        }
        #pragma unroll
        for (int m = 0; m < 4; ++m) {
            const int row = rg * 4 + m;
            nt_store4(&O[(size_t)row * DD + dc + cg * 4],
                      o[m][0], o[m][1], o[m][2], o[m][3]);
        }
        __syncthreads();
    }
}

extern "C" void kernel_launch(void* const* d_in, const int* in_sizes, int n_in,
                              void* d_out, int out_size, void* d_ws, size_t ws_size,
                              hipStream_t stream) {
    const float* q = (const float*)d_in[0];
    const float* k = (const float*)d_in[1];
    const float* v = (const float*)d_in[2];
    float* out = (float*)d_out;
    compute_kernel<<<dim3(COMPUTE_WGS), dim3(256), 0, stream>>>(q, k, v, out);
    fill_kernel<<<dim3(NFILL), dim3(256), 0, stream>>>(out);
}

// Round 5
// 134.903 us; speedup vs baseline: 1.1414x; 1.1414x over previous
//
#include <hip/hip_runtime.h>

#define BB 4
#define SS 4096
#define DD 512
#define BLK 64
#define COMPUTE_WGS 256
#define NFILL 2048
#define TOTAL_WGS (COMPUTE_WGS + NFILL)

#define ATTN_F4 ((unsigned)BB * SS * SS / 4)          // 16,777,216 = 16 * 1,048,576
#define MASK_F4 ((unsigned)SS * SS / 4)               //  4,194,304 =  4 * 1,048,576
// fill: 2048 wgs * 512 thr * 20 f4 = 20,971,520 f4 exactly (16 attn + 4 mask iters)

typedef float nf4 __attribute__((ext_vector_type(4)));

static __device__ __forceinline__ void nt_store4(float* p, float x, float y, float z, float w) {
    nf4 v = {x, y, z, w};
    __builtin_nontemporal_store(v, (nf4*)p);
}
static __device__ __forceinline__ void st_splat4(float* p, float x) {
    *(float4*)p = make_float4(x, x, x, x);   // normal (cached) store
}

__global__ __launch_bounds__(512)
void bla_kernel(const float* __restrict__ q,
                const float* __restrict__ k,
                const float* __restrict__ v,
                float* __restrict__ out)
{
    const float SCALE = 0.044194173824159216f;  // 1/sqrt(512)
    const int wg = blockIdx.x;
    const int t  = threadIdx.x;

    float* const attn = out + (size_t)BB * SS * DD;

    // ---------------- fill workgroups: normal streaming stores ----------------
    if (wg >= COMPUTE_WGS) {
        const unsigned fw = (unsigned)(wg - COMPUTE_WGS);
        const unsigned stride = (unsigned)NFILL * 512u;          // 1,048,576
        unsigned f = fw * 512u + (unsigned)t;
        // attn region: iterations 0..15 (f < ATTN_F4 guaranteed)
        #pragma unroll
        for (int it = 0; it < 16; ++it, f += stride) {
            const unsigned row = f >> 10;                        // 0..16383
            const unsigned c4b = (f & 1023u) >> 4;               // 16-f4 segment
            const unsigned qb  = (row & (SS - 1u)) >> 6;
            if (c4b != qb) st_splat4(&attn[(size_t)f * 4], 0.0f);
        }
        // mask region: iterations 16..19
        #pragma unroll
        for (int it = 0; it < 4; ++it, f += stride) {
            const unsigned g   = f - ATTN_F4;
            const unsigned row = g >> 10;                        // 0..4095
            const unsigned c4b = (g & 1023u) >> 4;
            st_splat4(&attn[(size_t)f * 4], (c4b == (row >> 6)) ? 1.0f : 0.0f);
        }
        return;
    }

    // ---------------- compute workgroups: one (b, block), 512 threads ----------------
    const int b   = wg >> 6;
    const int blk = wg & 63;
    const int q0  = blk * BLK;

    const float* Q = q + ((size_t)(b * SS + q0)) * DD;
    const float* K = k + ((size_t)(b * SS + q0)) * DD;
    const float* V = v + ((size_t)(b * SS + q0)) * DD;
    float* O = out + ((size_t)(b * SS + q0)) * DD;
    float* A = attn + (size_t)b * SS * SS + (size_t)q0 * SS + q0;

    __shared__ float qs[64][68];   // Q tile chunk; then S/P
    __shared__ float ks[64][68];   // K tile chunk; then V chunks

    const int gid = t >> 8;        // output-column group: 0 -> cols 0-31, 1 -> 32-63
    const int lt  = t & 255;
    const int rg  = lt >> 4;       // 0..15 -> rows rg*4+m
    const int cg  = lt & 15;

    // staging mapping: 2 float4 per thread per 64x64 chunk
    int srow[2], sc4[2];
    #pragma unroll
    for (int i = 0; i < 2; ++i) {
        const int j = t + i * 512;
        srow[i] = j >> 4;
        sc4[i]  = (j & 15) * 4;
    }

    float acc[4][2];
    #pragma unroll
    for (int m = 0; m < 4; ++m) { acc[m][0] = 0.0f; acc[m][1] = 0.0f; }

    // ---- phase 1: S = Q K^T, register double-buffered staging ----
    float4 pq[2], pk[2];
    #pragma unroll
    for (int i = 0; i < 2; ++i) {
        pq[i] = *(const float4*)&Q[(size_t)srow[i] * DD + sc4[i]];
        pk[i] = *(const float4*)&K[(size_t)srow[i] * DD + sc4[i]];
    }
    #pragma unroll
    for (int ch = 0; ch < 8; ++ch) {
        #pragma unroll
        for (int i = 0; i < 2; ++i) {
            *(float4*)&qs[srow[i]][sc4[i]] = pq[i];
            *(float4*)&ks[srow[i]][sc4[i]] = pk[i];
        }
        if (ch < 7) {
            const int dcn = (ch + 1) * 64;
            #pragma unroll
            for (int i = 0; i < 2; ++i) {
                pq[i] = *(const float4*)&Q[(size_t)srow[i] * DD + dcn + sc4[i]];
                pk[i] = *(const float4*)&K[(size_t)srow[i] * DD + dcn + sc4[i]];
            }
        }
        __syncthreads();
        #pragma unroll
        for (int c4 = 0; c4 < 64; c4 += 4) {
            float4 qv[4], kv[2];
            #pragma unroll
            for (int m = 0; m < 4; ++m) qv[m] = *(const float4*)&qs[rg * 4 + m][c4];
            #pragma unroll
            for (int n = 0; n < 2; ++n) kv[n] = *(const float4*)&ks[gid * 32 + cg + 16 * n][c4];
            #pragma unroll
            for (int m = 0; m < 4; ++m)
                #pragma unroll
                for (int n = 0; n < 2; ++n)
                    acc[m][n] += qv[m].x * kv[n].x + qv[m].y * kv[n].y
                               + qv[m].z * kv[n].z + qv[m].w * kv[n].w;
        }
        __syncthreads();
    }

    // issue V chunk-0 prefetch; latency hides under softmax
    float4 pv[2];
    #pragma unroll
    for (int i = 0; i < 2; ++i)
        pv[i] = *(const float4*)&V[(size_t)srow[i] * DD + sc4[i]];

    // ---- phase 2: scores -> LDS, wave-parallel softmax (8 threads/row) ----
    #pragma unroll
    for (int m = 0; m < 4; ++m)
        #pragma unroll
        for (int n = 0; n < 2; ++n)
            qs[rg * 4 + m][gid * 32 + cg + 16 * n] = acc[m][n] * SCALE;
    __syncthreads();

    {
        const int row  = t >> 3;          // 0..63
        const int part = t & 7;           // 8 cols each
        float4 s0 = *(const float4*)&qs[row][part * 8];
        float4 s1 = *(const float4*)&qs[row][part * 8 + 4];
        float mx = fmaxf(fmaxf(fmaxf(s0.x, s0.y), fmaxf(s0.z, s0.w)),
                         fmaxf(fmaxf(s1.x, s1.y), fmaxf(s1.z, s1.w)));
        #pragma unroll
        for (int s = 1; s < 8; s <<= 1) mx = fmaxf(mx, __shfl_xor(mx, s, 64));
        s0.x = __expf(s0.x - mx); s0.y = __expf(s0.y - mx);
        s0.z = __expf(s0.z - mx); s0.w = __expf(s0.w - mx);
        s1.x = __expf(s1.x - mx); s1.y = __expf(s1.y - mx);
        s1.z = __expf(s1.z - mx); s1.w = __expf(s1.w - mx);
        float sum = s0.x + s0.y + s0.z + s0.w + s1.x + s1.y + s1.z + s1.w;
        #pragma unroll
        for (int s = 1; s < 8; s <<= 1) sum += __shfl_xor(sum, s, 64);
        const float inv = 1.0f / sum;
        s0.x *= inv; s0.y *= inv; s0.z *= inv; s0.w *= inv;
        s1.x *= inv; s1.y *= inv; s1.z *= inv; s1.w *= inv;
        *(float4*)&qs[row][part * 8]     = s0;
        *(float4*)&qs[row][part * 8 + 4] = s1;
    }
    __syncthreads();

    // write attn band rows (P) from LDS: 2 float4 per thread
    #pragma unroll
    for (int i = 0; i < 2; ++i) {
        const int row = srow[i];
        const int c4  = sc4[i];
        nt_store4(&A[(size_t)row * SS + c4],
                  qs[row][c4], qs[row][c4 + 1], qs[row][c4 + 2], qs[row][c4 + 3]);
    }

    // ---- phase 3: O = P V; per-thread 2 rows x 4 cols (float4 output) ----
    const int rr = t >> 4;       // 0..31 -> rows rr*2+m
    const int cc = t & 15;       // f4 col cc -> cols 4cc..4cc+3
    #pragma unroll
    for (int ch = 0; ch < 8; ++ch) {
        const int dc = ch * 64;
        #pragma unroll
        for (int i = 0; i < 2; ++i)
            *(float4*)&ks[srow[i]][sc4[i]] = pv[i];
        if (ch < 7) {
            const int dcn = dc + 64;
            #pragma unroll
            for (int i = 0; i < 2; ++i)
                pv[i] = *(const float4*)&V[(size_t)srow[i] * DD + dcn + sc4[i]];
        }
        __syncthreads();
        float4 o0 = make_float4(0.f, 0.f, 0.f, 0.f);
        float4 o1 = make_float4(0.f, 0.f, 0.f, 0.f);
        #pragma unroll
        for (int k4 = 0; k4 < 64; k4 += 4) {
            float4 pw0 = *(const float4*)&qs[rr * 2 + 0][k4];
            float4 pw1 = *(const float4*)&qs[rr * 2 + 1][k4];
            #pragma unroll
            for (int kk = 0; kk < 4; ++kk) {
                const float4 vv = *(const float4*)&ks[k4 + kk][cc * 4];
                const float a0 = ((const float*)&pw0)[kk];
                const float a1 = ((const float*)&pw1)[kk];
                o0.x += a0 * vv.x; o0.y += a0 * vv.y; o0.z += a0 * vv.z; o0.w += a0 * vv.w;
                o1.x += a1 * vv.x; o1.y += a1 * vv.y; o1.z += a1 * vv.z; o1.w += a1 * vv.w;
            }
        }
        nt_store4(&O[(size_t)(rr * 2 + 0) * DD + dc + cc * 4], o0.x, o0.y, o0.z, o0.w);
        nt_store4(&O[(size_t)(rr * 2 + 1) * DD + dc + cc * 4], o1.x, o1.y, o1.z, o1.w);
        __syncthreads();
    }
}

extern "C" void kernel_launch(void* const* d_in, const int* in_sizes, int n_in,
                              void* d_out, int out_size, void* d_ws, size_t ws_size,
                              hipStream_t stream) {
    const float* q = (const float*)d_in[0];
    const float* k = (const float*)d_in[1];
    const float* v = (const float*)d_in[2];
    float* out = (float*)d_out;
    bla_kernel<<<dim3(TOTAL_WGS), dim3(512), 0, stream>>>(q, k, v, out);
}